// Round 2
// baseline (139.281 us; speedup 1.0000x reference)
//
#include <hip/hip_runtime.h>

// DotProductAttention: B=16, NQ=2048, NK=2048, D=128, DV=128, fp32 in/out.
// R8: LDS-bandwidth attack.
// (a) back to 4 waves x (32q x 32k) per 64-q task (256 thr): every K/V frag
//     feeds 2 MFMAs (R7's 16q waves were 1:1) -> per-tile LDS reads halve
//     (128KB -> 64KB per block-tile);
// (b) keep R7's in-register P (swapped QK^T + cvt_pk + permlane32/16_swap,
//     no Pb LDS, scalar l per q16);
// (c) XCD-pinned pairing schedule: task e -> pair p=e&7; round-robin dispatch
//     puts both batches of pair p on XCD p -> 2MB KV per XCD, L2-resident.

#define B_   16
#define NQ_  2048
#define NK_  2048
#define D_   128
#define DV_  128
#define NTASK_ 512

typedef unsigned short ushort;
typedef __attribute__((ext_vector_type(4))) float          f32x4;
typedef __attribute__((ext_vector_type(8))) __bf16         bf16x8;
typedef __attribute__((ext_vector_type(8))) unsigned short ushort8v;
typedef __attribute__((ext_vector_type(4))) unsigned int   uint4v;

#ifdef __has_builtin
#if __has_builtin(__builtin_amdgcn_cvt_pk_bf16_f32)
#define HAVE_CVT_PK_BF16 1
#endif
#endif

__device__ __forceinline__ ushort f2bf(float f) {
    unsigned u = __builtin_bit_cast(unsigned, f);
    return (ushort)((u + 0x8000u) >> 16);
}
__device__ __forceinline__ unsigned f2bf2(float a, float b) {
#ifdef HAVE_CVT_PK_BF16
    auto t = __builtin_amdgcn_cvt_pk_bf16_f32(a, b);
    return __builtin_bit_cast(unsigned, t);
#else
    return (unsigned)f2bf(a) | ((unsigned)f2bf(b) << 16);
#endif
}
// sum of the two bf16 values packed in u (exactly the values PV consumes)
__device__ __forceinline__ float bfpair_sum(unsigned u) {
    float lo = __builtin_bit_cast(float, u << 16);
    float hi = __builtin_bit_cast(float, u & 0xffff0000u);
    return lo + hi;
}
__device__ __forceinline__ void gl_lds16(const ushort* g, ushort* l) {
    __builtin_amdgcn_global_load_lds(
        (const __attribute__((address_space(1))) void*)g,
        (__attribute__((address_space(3))) void*)l, 16, 0, 0);
}

// Pre-pass: per (b, k-tile): K -> bf16 tile [key64][d128], 16B-unit swizzle
// (d-unit du stored at du ^ (key&7)); V -> bf16 transposed [dv128][key64],
// key-unit kg stored at kg ^ (dv&7). Tiles contiguous. (unchanged)
__global__ __launch_bounds__(256) void convert_kv(
    const float* __restrict__ K, const float* __restrict__ V,
    const int* __restrict__ vlen, ushort* __restrict__ Kb, ushort* __restrict__ Vtb)
{
    const int id = blockIdx.x;              // 512 = 16 b x 32 tiles
    const int b  = id & 15, kt = id >> 4;
    if (kt >= ((vlen[b] + 63) >> 6)) return;
    const int tid = threadIdx.x;
    const float* gK = K + ((size_t)b * NK_ + kt * 64) * D_;
    const float* gV = V + ((size_t)b * NK_ + kt * 64) * DV_;
    ushort* tK = Kb  + ((size_t)b * 32 + kt) * 8192;
    ushort* tV = Vtb + ((size_t)b * 32 + kt) * 8192;

    #pragma unroll
    for (int i = 0; i < 4; ++i) {           // 1024 K units: key = u>>4, d-unit = u&15
        int u = i * 256 + tid;
        int key = u >> 4, d8 = u & 15;
        const float* p = gK + key * D_ + d8 * 8;
        f32x4 a0 = *(const f32x4*)p;
        f32x4 a1 = *(const f32x4*)(p + 4);
        uint4v w;
        w[0] = f2bf2(a0[0], a0[1]); w[1] = f2bf2(a0[2], a0[3]);
        w[2] = f2bf2(a1[0], a1[1]); w[3] = f2bf2(a1[2], a1[3]);
        *(uint4v*)&tK[key * 128 + ((d8 ^ (key & 7)) << 3)] = w;
    }
    #pragma unroll
    for (int i = 0; i < 4; ++i) {           // 1024 V units: dv = u&127, key-grp = u>>7
        int u = i * 256 + tid;
        int dv = u & 127, kg = u >> 7;
        const float* vp = gV + (size_t)(kg * 8) * DV_ + dv;
        float v[8];
        #pragma unroll
        for (int j = 0; j < 8; ++j) v[j] = vp[(size_t)j * DV_];
        uint4v w;
        w[0] = f2bf2(v[0], v[1]); w[1] = f2bf2(v[2], v[3]);
        w[2] = f2bf2(v[4], v[5]); w[3] = f2bf2(v[6], v[7]);
        *(uint4v*)&tV[dv * 64 + ((kg ^ (dv & 7)) << 3)] = w;
    }
}

__global__ __launch_bounds__(256, 2) void attn_fwd(
    const float* __restrict__ Q, const int* __restrict__ vlen,
    const ushort* __restrict__ Kb, const ushort* __restrict__ Vtb,
    float* __restrict__ Out)
{
    // double-buffered K|V tiles (bf16, swizzled): [buf][ K 8192 | V 8192 ]
    __shared__ ushort KVbuf[2][16384];                 // 64 KB
    __shared__ float  lsh[2][64];
    __shared__ int    ssch[16];
    float* Osh = (float*)&KVbuf[0][0];                 // epilogue alias: [wk][64q][128dv]

    const int tid  = threadIdx.x;     // 0..255
    const int w    = tid >> 6;        // 0..3
    const int wq   = w >> 1;          // q-half owner (32 rows)
    const int wk   = w & 1;           // key-half (32 keys)
    const int L    = tid & 63;
    const int col  = L & 15;
    const int quad = L >> 4;

    // ---- inline schedule: rank batches by vl desc
    if (tid < 16) {
        int my = vlen[tid];
        int rank = 0;
        for (int o = 0; o < 16; ++o) {
            int vo = vlen[o];
            if (vo > my || (vo == my && o < tid)) ++rank;
        }
        ssch[rank] = tid;
    }
    __syncthreads();

    // XCD-pinned pairing: pair p = e&7 -> XCD p (round-robin dispatch).
    const int e     = blockIdx.x;
    const int p_    = e & 7;
    const int b     = ((e >> 3) & 1) ? ssch[15 - p_] : ssch[p_];
    const int qbase = (e >> 4) * 64;
    const int vl    = vlen[b];
    const int ntiles = (vl + 63) >> 6;

    // ---- Q fragments: 2 x (16 rows), pre-scaled by log2(e)/sqrt(128)
    const float qscale = 0.12751743f;
    bf16x8 qf[2][4];
    #pragma unroll
    for (int q16 = 0; q16 < 2; ++q16) {
        const int qrow = qbase + wq * 32 + q16 * 16 + col;
        const float* gQ = Q + ((size_t)b * NQ_ + qrow) * D_;
        #pragma unroll
        for (int c = 0; c < 4; ++c) {
            const float* pp = gQ + c * 32 + quad * 8;
            f32x4 a0 = *(const f32x4*)pp;
            f32x4 a1 = *(const f32x4*)(pp + 4);
            uint4v us;
            us[0] = f2bf2(a0[0] * qscale, a0[1] * qscale);
            us[1] = f2bf2(a0[2] * qscale, a0[3] * qscale);
            us[2] = f2bf2(a1[0] * qscale, a1[1] * qscale);
            us[3] = f2bf2(a1[2] * qscale, a1[3] * qscale);
            qf[q16][c] = __builtin_bit_cast(bf16x8, us);
        }
    }

    // ---- accumulators: partial O over own key-half, full 128 dv; scalar l/q16
    f32x4 o[2][8];
    #pragma unroll
    for (int q16 = 0; q16 < 2; ++q16)
        #pragma unroll
        for (int d = 0; d < 8; ++d) o[q16][d] = (f32x4){0.f, 0.f, 0.f, 0.f};
    float l_run[2] = {0.f, 0.f};

    const ushort* tKb = Kb  + (size_t)b * 32 * 8192;
    const ushort* tVb = Vtb + (size_t)b * 32 * 8192;

    #define ISSUE_DMA(KT, BUF)                                               \
        do {                                                                 \
            const ushort* gk = tKb + (size_t)(KT) * 8192;                    \
            const ushort* gv = tVb + (size_t)(KT) * 8192;                    \
            _Pragma("unroll")                                                \
            for (int i = 0; i < 4; ++i) {                                    \
                int off = (i * 256 + tid) * 8;                               \
                gl_lds16(gk + off, &KVbuf[BUF][off]);                        \
                gl_lds16(gv + off, &KVbuf[BUF][8192 + off]);                 \
            }                                                                \
        } while (0)

    ISSUE_DMA(0, 0);

    const int swz = col & 7;

    for (int kt = 0; kt < ntiles; ++kt) {
        const int buf = kt & 1;
        __syncthreads();   // drains DMA(kt) only (nothing else outstanding)
        if (kt + 1 < ntiles) ISSUE_DMA(kt + 1, buf ^ 1);

        const ushort* Kt = &KVbuf[buf][0];
        const ushort* Vt = &KVbuf[buf][8192];

        // ---- S^T = K Q^T (swapped): lane holds S[q=col][key=kc*16+quad*4+r]
        // each K fragment feeds BOTH q16 MFMAs (2x register reuse)
        f32x4 s[2][2];
        #pragma unroll
        for (int q16 = 0; q16 < 2; ++q16)
            #pragma unroll
            for (int kc = 0; kc < 2; ++kc) s[q16][kc] = (f32x4){0.f,0.f,0.f,0.f};
        __builtin_amdgcn_s_setprio(1);
        #pragma unroll
        for (int kc = 0; kc < 2; ++kc) {
            const int kbase = (wk * 32 + kc * 16 + col) * 128;
            #pragma unroll
            for (int c = 0; c < 4; ++c) {
                bf16x8 kb = __builtin_bit_cast(bf16x8, *(const ushort8v*)
                    &Kt[kbase + (((c * 4 + quad) ^ swz) << 3)]);
                s[0][kc] = __builtin_amdgcn_mfma_f32_16x16x32_bf16(kb, qf[0][c], s[0][kc], 0, 0, 0);
                s[1][kc] = __builtin_amdgcn_mfma_f32_16x16x32_bf16(kb, qf[1][c], s[1][kc], 0, 0, 0);
            }
        }
        __builtin_amdgcn_s_setprio(0);

        // ---- mask (key rows lane-indexed); exp2(-1e30) == 0
        const int rem = vl - kt * 64 - wk * 32;   // valid keys in this half
        if (rem < 32) {
            #pragma unroll
            for (int rr = 0; rr < 4; ++rr) {
                if (quad * 4 + rr >= rem) {
                    s[0][0][rr] = -1e30f; s[1][0][rr] = -1e30f;
                }
                if (16 + quad * 4 + rr >= rem) {
                    s[0][1][rr] = -1e30f; s[1][1][rr] = -1e30f;
                }
            }
        }

        // ---- p = exp2(s) -> packed bf16; in-register C->A transpose per q16
        bf16x8 pa[2];
        #pragma unroll
        for (int q16 = 0; q16 < 2; ++q16) {
            unsigned wA = f2bf2(exp2f(s[q16][0][0]), exp2f(s[q16][0][1]));
            unsigned wB = f2bf2(exp2f(s[q16][0][2]), exp2f(s[q16][0][3]));
            unsigned wC = f2bf2(exp2f(s[q16][1][0]), exp2f(s[q16][1][1]));
            unsigned wD = f2bf2(exp2f(s[q16][1][2]), exp2f(s[q16][1][3]));
            l_run[q16] += bfpair_sum(wA) + bfpair_sum(wB) + bfpair_sum(wC) + bfpair_sum(wD);
            asm("v_permlane32_swap_b32 %0, %1" : "+v"(wA), "+v"(wC));
            asm("v_permlane32_swap_b32 %0, %1" : "+v"(wB), "+v"(wD));
            asm("v_permlane16_swap_b32 %0, %1" : "+v"(wA), "+v"(wC));
            asm("v_permlane16_swap_b32 %0, %1" : "+v"(wB), "+v"(wD));
            uint4v pw;
            pw[0] = wA; pw[1] = wB; pw[2] = wC; pw[3] = wD;
            pa[q16] = __builtin_bit_cast(bf16x8, pw);
        }

        // ---- O_partial += P_own(32q x 32k) V_own(32k x 128dv); V reused 2x
        __builtin_amdgcn_s_setprio(1);
        #pragma unroll
        for (int dvc = 0; dvc < 8; ++dvc) {
            const int dv = dvc * 16 + col;
            bf16x8 vb = __builtin_bit_cast(bf16x8, *(const ushort8v*)
                &Vt[dv * 64 + (((wk * 4 + quad) ^ swz) << 3)]);
            o[0][dvc] = __builtin_amdgcn_mfma_f32_16x16x32_bf16(pa[0], vb, o[0][dvc], 0, 0, 0);
            o[1][dvc] = __builtin_amdgcn_mfma_f32_16x16x32_bf16(pa[1], vb, o[1][dvc], 0, 0, 0);
        }
        __builtin_amdgcn_s_setprio(0);
    }
    #undef ISSUE_DMA

    // ---- l: sum the 4 quads holding the same q=col
    #pragma unroll
    for (int q16 = 0; q16 < 2; ++q16) {
        l_run[q16] += __shfl_xor(l_run[q16], 16, 64);
        l_run[q16] += __shfl_xor(l_run[q16], 32, 64);
    }

    __syncthreads();   // everyone done with KVbuf before aliasing as Osh

    if (L < 16) {
        lsh[wk][wq * 32 + L]      = l_run[0];
        lsh[wk][wq * 32 + 16 + L] = l_run[1];
    }
    #pragma unroll
    for (int q16 = 0; q16 < 2; ++q16)
        #pragma unroll
        for (int dvc = 0; dvc < 8; ++dvc)
            #pragma unroll
            for (int rr = 0; rr < 4; ++rr)
                Osh[wk * 8192 + (wq * 32 + q16 * 16 + quad * 4 + rr) * 128 + dvc * 16 + col]
                    = o[q16][dvc][rr];
    __syncthreads();

    // ---- combine wk halves, normalize, coalesced store
    float* gO = Out + ((size_t)b * NQ_ + qbase) * DV_;
    #pragma unroll
    for (int i = 0; i < 8; ++i) {
        int idx = i * 256 + tid;           // f32x4 chunk id, row-major
        int row = idx >> 5;
        int dq  = idx & 31;
        f32x4 a0 = *(const f32x4*)&Osh[row * 128 + dq * 4];
        f32x4 a1 = *(const f32x4*)&Osh[8192 + row * 128 + dq * 4];
        float linv = 1.0f / (lsh[0][row] + lsh[1][row]);
        *(f32x4*)&gO[(size_t)row * DV_ + dq * 4] = (a0 + a1) * linv;
    }
}

extern "C" void kernel_launch(void* const* d_in, const int* in_sizes, int n_in,
                              void* d_out, int out_size, void* d_ws, size_t ws_size,
                              hipStream_t stream) {
    const float* Q  = (const float*)d_in[0];
    const float* K  = (const float*)d_in[1];
    const float* V  = (const float*)d_in[2];
    const int*   vl = (const int*)d_in[3];
    float* out = (float*)d_out;

    // ws: [0,4K) reserved | [4K, +8.39M) Kb | [next, +8.39M) Vtb  (~16.8 MB)
    char* ws = (char*)d_ws;
    ushort* Kbuf = (ushort*)(ws + 4096);
    ushort* Vbuf = Kbuf + (size_t)B_ * 32 * 8192;

    convert_kv<<<dim3(512, 1, 1), dim3(256, 1, 1), 0, stream>>>(K, V, vl, Kbuf, Vbuf);
    attn_fwd<<<dim3(NTASK_, 1, 1), dim3(256, 1, 1), 0, stream>>>(
        Q, vl, Kbuf, Vbuf, out);
}